// Round 2
// 575.074 us; speedup vs baseline: 1.2383x; 1.2383x over previous
//
#include <hip/hip_runtime.h>

// SDE scan: B=2048 rows, T=512 steps, FS=32, FA=16, H=64.
// One wave per batch row; T-loop in-kernel (recurrence is per-row).
// R3 (resubmit after infra failure): layer-1 operand broadcast moved from
//     v_readlane (VALU pipe, 48 ops/step) to LDS broadcast reads (DS pipe,
//     12 ds_read_b128/step, same-address broadcast = conflict-free).
//     x-state round-trips through xbuf[32]; a-quad transposed into
//     double-buffered abuf by lanes 0-15.
//     FMA order preserved exactly -> bit-identical results vs R2.

#define SQRT_DT_F 0.22360679774997896f

__device__ __forceinline__ float fast_tanh(float y) {
    // tanh(y) = 1 - 2/(exp(2y)+1); stable at both extremes
    float e = __expf(2.0f * y);
    return 1.0f - 2.0f / (e + 1.0f);
}

__device__ __forceinline__ void wave_sync() {
    // Single-wave block: DS pipe is in-order within a wave; we only need to
    // stop the compiler moving DS ops across this point. Everything else
    // (VALU/SALU/VMEM/trans) may cross freely.
    __builtin_amdgcn_fence(__ATOMIC_SEQ_CST, "wavefront");
    __builtin_amdgcn_sched_barrier(0x047F);
}

__global__ __launch_bounds__(64, 2)
void sde_kernel(const float* __restrict__ in_signal,   // (B,16,512)
                const float* __restrict__ x0v,         // (B,32)
                const float* __restrict__ noise,       // (511,B,32)
                const float* __restrict__ Wf1, const float* __restrict__ bf1,
                const float* __restrict__ Wf2, const float* __restrict__ bf2,
                const float* __restrict__ Wg1, const float* __restrict__ bg1,
                const float* __restrict__ Wg2, const float* __restrict__ bg2,
                float* __restrict__ out)               // (B,32,512)
{
    const int lane = threadIdx.x;   // 0..63
    const int b    = blockIdx.x;    // batch row

    __shared__ __align__(16) float hbuf[2][128];   // [parity][hf(64), hg(64)]
    __shared__ __align__(16) float xbuf[32];       // broadcast x-state
    __shared__ __align__(16) float abuf[2][4][16]; // [quad parity][tt][k]

    // ---- weights -> registers (one-time, coalesced) ----
    float w1f[48], w1g[48];
#pragma unroll
    for (int k = 0; k < 48; ++k) {
        w1f[k] = Wf1[k * 64 + lane];
        w1g[k] = Wg1[k * 64 + lane];
    }
    float w2[64];
    const float* W2p = (lane < 32) ? (Wf2 + lane) : (Wg2 + (lane - 32));
#pragma unroll
    for (int j = 0; j < 64; ++j) w2[j] = W2p[j * 32];

    const float b1f = bf1[lane];
    const float b1g = bg1[lane];
    const float b2  = (lane < 32) ? bf2[lane] : bg2[lane - 32];

    // ---- state init ----
    float x_init = x0v[b * 32 + (lane & 31)];
    if (lane < 32) xbuf[lane] = x_init;

    const float* hsrc0 = hbuf[0] + ((lane >> 5) << 6);   // hf or hg, parity 0
    const float* hsrc1 = hbuf[1] + ((lane >> 5) << 6);   // parity 1
    const float* a_base = in_signal + ((size_t)(b * 16 + (lane & 15)) << 9);
    const float* noise_lane = noise + (size_t)b * 32 + (lane & 31);
    float* out_ptr = out + ((size_t)b * 32 + (lane & 31)) * 512;

    // prefetch eps two steps ahead
    float eps_c = noise_lane[0];                 // t = 0
    float eps_n = noise_lane[65536];             // t = 1

    {   // quad 0 a-values -> abuf[0] (transposed by lanes 0-15)
        float4 a0 = *(const float4*)(a_base);
        if (lane < 16) {
            abuf[0][0][lane] = a0.x;
            abuf[0][1][lane] = a0.y;
            abuf[0][2][lane] = a0.z;
            abuf[0][3][lane] = a0.w;
        }
    }
    float xq[4];
    xq[0] = x_init;
    wave_sync();

#define STEP(tt) do {                                                           \
    const int t_ = tq4 + (tt);                                                  \
    /* prefetch eps for step t+2 (~2 steps of latency cover) */                 \
    int tf_ = t_ + 2; if (tf_ > 510) tf_ = 510;                                 \
    float eps_f = noise_lane[(size_t)tf_ << 16];                                \
    /* layer-1 operands via LDS broadcast reads (no readlane) */                \
    float sa[16], sx[32];                                                       \
    *(float4*)&sa[0]  = *(const float4*)&ab_[tt][0];                            \
    *(float4*)&sa[4]  = *(const float4*)&ab_[tt][4];                            \
    *(float4*)&sa[8]  = *(const float4*)&ab_[tt][8];                            \
    *(float4*)&sa[12] = *(const float4*)&ab_[tt][12];                           \
    _Pragma("unroll")                                                           \
    for (int q = 0; q < 8; ++q)                                                 \
        *(float4*)&sx[q * 4] = *(const float4*)&xbuf[q * 4];                    \
    /* layer 1: lane j -> hf_j, hg_j ; dual accumulator chains */               \
    float accf0 = b1f, accf1 = 0.f, accg0 = b1g, accg1 = 0.f;                   \
    _Pragma("unroll")                                                           \
    for (int k = 0; k < 16; k += 2) {                                           \
        accf0 = fmaf(sa[k],     w1f[k],     accf0);                             \
        accg0 = fmaf(sa[k],     w1g[k],     accg0);                             \
        accf1 = fmaf(sa[k + 1], w1f[k + 1], accf1);                             \
        accg1 = fmaf(sa[k + 1], w1g[k + 1], accg1);                             \
    }                                                                           \
    _Pragma("unroll")                                                           \
    for (int i = 0; i < 32; i += 2) {                                           \
        accf0 = fmaf(sx[i],     w1f[16 + i], accf0);                            \
        accg0 = fmaf(sx[i],     w1g[16 + i], accg0);                            \
        accf1 = fmaf(sx[i + 1], w1f[17 + i], accf1);                            \
        accg1 = fmaf(sx[i + 1], w1g[17 + i], accg1);                            \
    }                                                                           \
    float hfv = fast_tanh(accf0 + accf1);                                       \
    float hgv = fast_tanh(accg0 + accg1);                                       \
    hbuf[(tt) & 1][lane]      = hfv;                                            \
    hbuf[(tt) & 1][64 + lane] = hgv;                                            \
    wave_sync();                                                                \
    /* layer 2: lanes 0-31 drift_i (hf), lanes 32-63 diff-pre_i (hg) */         \
    {                                                                           \
        const float* hs_ = ((tt) & 1) ? hsrc1 : hsrc0;                          \
        float acc2a = b2, acc2b = 0.f;                                          \
        _Pragma("unroll")                                                       \
        for (int j0 = 0; j0 < 64; j0 += 8) {                                    \
            const float4 ha = *(const float4*)&hs_[j0];                         \
            const float4 hb = *(const float4*)&hs_[j0 + 4];                     \
            acc2a = fmaf(ha.x, w2[j0 + 0], acc2a);                              \
            acc2b = fmaf(hb.x, w2[j0 + 4], acc2b);                              \
            acc2a = fmaf(ha.y, w2[j0 + 1], acc2a);                              \
            acc2b = fmaf(hb.y, w2[j0 + 5], acc2b);                              \
            acc2a = fmaf(ha.z, w2[j0 + 2], acc2a);                              \
            acc2b = fmaf(hb.z, w2[j0 + 6], acc2b);                              \
            acc2a = fmaf(ha.w, w2[j0 + 3], acc2a);                              \
            acc2b = fmaf(hb.w, w2[j0 + 7], acc2b);                              \
        }                                                                       \
        float acc2 = acc2a + acc2b;                                             \
        float other = __shfl_xor(acc2, 32, 64);                                 \
        float drift = (lane < 32) ? acc2 : other;                               \
        float gpre  = (lane < 32) ? other : acc2;                               \
        float xi = fmaf(gpre, eps_c * SQRT_DT_F, drift);                        \
        xi = fminf(5.0f, fmaxf(-5.0f, xi));                                     \
        if (lane < 32) xbuf[lane] = xi;   /* early write: covered by next     */\
        xq[((tt) + 1) & 3] = xi;          /* step's a-reads + a-FMAs          */\
        if ((tt) == 2) {                                                        \
            if (lane < 32)                                                      \
                *(float4*)(out_ptr + tq4) =                                     \
                    make_float4(xq[0], xq[1], xq[2], xq[3]);                    \
        }                                                                       \
    }                                                                           \
    wave_sync();                                                                \
    eps_c = eps_n; eps_n = eps_f;                                               \
} while (0)

    // main: t = 0..507 (127 quads)
    for (int tq = 0; tq < 127; ++tq) {
        const int tq4 = tq * 4;
        const float (*ab_)[16] = abuf[tq & 1];
        float4 aq_n = *(const float4*)(a_base + tq4 + 4);   // quad tq+1
        STEP(0);
        // stage next quad's a-values (parity flip; current quad reads ab_)
        if (lane < 16) {
            float (*abn)[16] = abuf[(tq + 1) & 1];
            abn[0][lane] = aq_n.x;
            abn[1][lane] = aq_n.y;
            abn[2][lane] = aq_n.z;
            abn[3][lane] = aq_n.w;
        }
        STEP(1); STEP(2); STEP(3);
    }
    // tail: t = 508, 509, 510  (store of [508..511] fires at tt==2)
    {
        const int tq4 = 508;
        const float (*ab_)[16] = abuf[127 & 1];
        STEP(0); STEP(1); STEP(2);
    }
#undef STEP
}

extern "C" void kernel_launch(void* const* d_in, const int* in_sizes, int n_in,
                              void* d_out, int out_size, void* d_ws, size_t ws_size,
                              hipStream_t stream) {
    // inputs: 0 ts(unused), 1 in_signal, 2 x0, 3 noise, 4 Wf1, 5 bf1, 6 Wf2,
    //         7 bf2, 8 Wg1, 9 bg1, 10 Wg2, 11 bg2
    const float* in_signal = (const float*)d_in[1];
    const float* x0v   = (const float*)d_in[2];
    const float* noise = (const float*)d_in[3];
    const float* Wf1 = (const float*)d_in[4];
    const float* bf1 = (const float*)d_in[5];
    const float* Wf2 = (const float*)d_in[6];
    const float* bf2 = (const float*)d_in[7];
    const float* Wg1 = (const float*)d_in[8];
    const float* bg1 = (const float*)d_in[9];
    const float* Wg2 = (const float*)d_in[10];
    const float* bg2 = (const float*)d_in[11];
    float* out = (float*)d_out;

    hipLaunchKernelGGL(sde_kernel, dim3(2048), dim3(64), 0, stream,
                       in_signal, x0v, noise, Wf1, bf1, Wf2, bf2,
                       Wg1, bg1, Wg2, bg2, out);
}